// Round 10
// baseline (179.152 us; speedup 1.0000x reference)
//
#include <hip/hip_runtime.h>
#include <math.h>

#define N_PTS 8192
#define HIDDEN 256
#define PPB 4                   // points per block
#define THREADS 256             // 4 waves
#define NBLK (N_PTS / PPB)      // 2048
#define NBINS 64
#define LDA 264                 // A row stride in shorts (528 B, 16B-aligned)
#define AROWS 32
#define LDZ 264                 // final-H f32 row stride
#define BP_OFF 4096             // byte offset of packed W in d_ws

typedef float f32x4 __attribute__((ext_vector_type(4)));
typedef short s8v  __attribute__((ext_vector_type(8)));
typedef short s4v  __attribute__((ext_vector_type(4)));

__device__ __forceinline__ unsigned short bf16_rne(float x) {
    unsigned int u = __float_as_uint(x);
    return (unsigned short)((u + 0x7FFFu + ((u >> 16) & 1u)) >> 16);
}
__device__ __forceinline__ float bf16f(unsigned short h) {
    return __uint_as_float(((unsigned int)h) << 16);
}
// row of (stream s, point p): point-local, 2 M-tiles, pads at 16+4p+3
__device__ __forceinline__ int rowof(int s, int p) {
    return (s < 4) ? (4 * p + s) : (16 + 4 * p + (s - 4));
}

// ---------------------------------------------------------------------------
// Pack W1..W3 into MFMA B-frag order with the k-slot permutation:
// slot sigma holds neuron j = 64*(sigma>>6) + 16*(sigma&3) + ((sigma>>2)&15).
// Lane l supplies B[k = slot(kc*32 + (l>>4)*8 + i)][n = nt*16 + (l&15)].
// Also zeroes bins + finalize counter (bins[0..519]).
// ---------------------------------------------------------------------------
__global__ void pinn_pack(const float* __restrict__ W1, const float* __restrict__ W2,
                          const float* __restrict__ W3, unsigned short* __restrict__ Bp,
                          float* __restrict__ bins)
{
    const int id = blockIdx.x * 64 + threadIdx.x;    // 0..24575 (384 blocks x 64)
    if (id < 520) bins[id] = 0.f;                    // 512 bins + cnt
    const int lane = id & 63;
    const int nt   = (id >> 6) & 15;
    const int kc   = (id >> 10) & 7;
    const int l    = id >> 13;                        // 0..2
    const float* W = (l == 0) ? W1 : ((l == 1) ? W2 : W3);
    const int n  = nt * 16 + (lane & 15);
    unsigned short hi[8], lo[8];
    #pragma unroll
    for (int i = 0; i < 8; ++i) {
        const int kslot = kc * 32 + (lane >> 4) * 8 + i;
        const int korig = ((kslot >> 6) & 3) * 64 + (kslot & 3) * 16 + ((kslot >> 2) & 15);
        const float x = W[(size_t)korig * HIDDEN + n];
        const unsigned short h = bf16_rne(x);
        hi[i] = h;
        lo[i] = bf16_rne(x - bf16f(h));
    }
    const size_t bh = ((((size_t)(l * 2 + 0) * 8 + kc) * 16 + nt) * 64 + lane) * 8;
    const size_t bl = ((((size_t)(l * 2 + 1) * 8 + kc) * 16 + nt) * 64 + lane) * 8;
    *(s8v*)&Bp[bh] = *(const s8v*)hi;
    *(s8v*)&Bp[bl] = *(const s8v*)lo;
}

// ---------------------------------------------------------------------------
// Main: second-order forward-mode MLP via split-bf16 MFMA + physics.
// PPB=4, 32-row A -> 33.8 KB LDS -> 4 blocks/CU (latency hiding was the r7
// limiter).  Nonlinearity fully in C-registers (lane g owns point g).
// ---------------------------------------------------------------------------
__global__ __launch_bounds__(THREADS, 4)
void pinn_main(const float* __restrict__ W0, const float* __restrict__ b0,
               const float* __restrict__ b1, const float* __restrict__ b2,
               const float* __restrict__ b3,
               const float* __restrict__ W4, const float* __restrict__ b4,
               const float* __restrict__ xin, const float* __restrict__ tin,
               const unsigned short* __restrict__ Bp,
               float* __restrict__ bins, float* __restrict__ out)
{
    __shared__ __align__(16) unsigned char LB[AROWS * LDA * 4];   // 33792 B
    __shared__ unsigned flagS;
    short* __restrict__ AhS = (short*)LB;
    short* __restrict__ AlS = (short*)(LB + AROWS * LDA * 2);
    float* __restrict__ Zf  = (float*)LB;               // final-H alias (32x264 f32)

    const int tid  = threadIdx.x;
    const int lane = tid & 63;
    const int w    = tid >> 6;          // wave 0..3
    const int c    = lane & 15;
    const int g    = lane >> 4;
    const int pt0  = blockIdx.x * PPB;
    unsigned* cnt  = (unsigned*)(bins + 512);

    // ---- layer 0 (3 -> 256): thread (c0i,w0i) -> slots 4(c0i+16w0i)+nn,
    //      cols j = 64*w0i + 16*nn + c0i; point pp = tid>>6 ----
    {
        const int c0i = tid & 15, w0i = (tid >> 4) & 3, pp = tid >> 6;
        float w0v[4], w1v[4], w2v[4], bbv[4];
        #pragma unroll
        for (int nn = 0; nn < 4; ++nn) {
            const int j = w0i * 64 + 16 * nn + c0i;
            w0v[nn] = W0[j]; w1v[nn] = W0[HIDDEN + j]; w2v[nn] = W0[2 * HIDDEN + j];
            bbv[nn] = b0[j];
        }
        const int sbase = 4 * (c0i + 16 * w0i);
        const float x0 = xin[(pt0 + pp) * 2 + 0];
        const float x1 = xin[(pt0 + pp) * 2 + 1];
        const float tt = tin[pt0 + pp];
        s4v hi[7], lo[7];
        #pragma unroll
        for (int nn = 0; nn < 4; ++nn) {
            const float z  = fmaf(x0, w0v[nn], fmaf(x1, w1v[nn], fmaf(tt, w2v[nn], bbv[nn])));
            const float a  = tanhf(z);
            const float st = 1.f - a * a;
            const float m2 = -2.f * a * st;
            float v[7];
            v[0] = a;
            v[1] = st * w0v[nn]; v[2] = st * w1v[nn]; v[3] = st * w2v[nn];
            v[4] = m2 * w0v[nn] * w0v[nn];
            v[5] = m2 * w0v[nn] * w1v[nn];
            v[6] = m2 * w1v[nn] * w1v[nn];
            #pragma unroll
            for (int s = 0; s < 7; ++s) {
                const unsigned short h = bf16_rne(v[s]);
                hi[s][nn] = (short)h;
                lo[s][nn] = (short)bf16_rne(v[s] - bf16f(h));
            }
        }
        #pragma unroll
        for (int s = 0; s < 7; ++s) {
            const int r = rowof(s, pp);
            *(s4v*)&AhS[r * LDA + sbase] = hi[s];
            *(s4v*)&AlS[r * LDA + sbase] = lo[s];
        }
        const s4v z4 = {0, 0, 0, 0};
        const int rp = 16 + 4 * pp + 3;              // pad row of this point
        *(s4v*)&AhS[rp * LDA + sbase] = z4;
        *(s4v*)&AlS[rp * LDA + sbase] = z4;
    }
    __syncthreads();

    // per-thread A-frag row offsets
    int aoff[2];
    #pragma unroll
    for (int mt = 0; mt < 2; ++mt) aoff[mt] = (16 * mt + c) * LDA + g * 8;

    // ---- hidden layers: split-bf16 MFMA matmul + in-register nonlinearity ----
    for (int l = 0; l < 3; ++l) {
        f32x4 acc[2][4];
        #pragma unroll
        for (int mt = 0; mt < 2; ++mt)
            #pragma unroll
            for (int nn = 0; nn < 4; ++nn) acc[mt][nn] = (f32x4)0.f;

        const size_t lbase = (size_t)l * 2 * 8 * 16 * 64 * 8;
        #pragma unroll
        for (int kc = 0; kc < 8; ++kc) {
            s8v ah[2], al[2];
            #pragma unroll
            for (int mt = 0; mt < 2; ++mt) {
                ah[mt] = *(const s8v*)&AhS[aoff[mt] + kc * 32];
                al[mt] = *(const s8v*)&AlS[aoff[mt] + kc * 32];
            }
            s8v bh[4], bl[4];
            #pragma unroll
            for (int nn = 0; nn < 4; ++nn) {
                const int nt = w * 4 + nn;
                const size_t oh = lbase + (((size_t)kc * 16 + nt) * 64 + lane) * 8;
                const size_t ol = oh + (size_t)8 * 16 * 64 * 8;
                bh[nn] = *(const s8v*)&Bp[oh];
                bl[nn] = *(const s8v*)&Bp[ol];
            }
            #pragma unroll
            for (int mt = 0; mt < 2; ++mt)
                #pragma unroll
                for (int nn = 0; nn < 4; ++nn) {
                    acc[mt][nn] = __builtin_amdgcn_mfma_f32_16x16x32_bf16(ah[mt], bh[nn], acc[mt][nn], 0, 0, 0);
                    acc[mt][nn] = __builtin_amdgcn_mfma_f32_16x16x32_bf16(ah[mt], bl[nn], acc[mt][nn], 0, 0, 0);
                    acc[mt][nn] = __builtin_amdgcn_mfma_f32_16x16x32_bf16(al[mt], bh[nn], acc[mt][nn], 0, 0, 0);
                }
        }
        __syncthreads();                     // all A reads done -> safe to overwrite

        // ---- boundary: lane (c,g) owns point g, cols 64w+16nn+c ----
        const float* bias = (l == 0) ? b1 : (l == 1) ? b2 : b3;
        float bbv[4];
        #pragma unroll
        for (int nn = 0; nn < 4; ++nn) bbv[nn] = bias[64 * w + 16 * nn + c];
        const int sbase = 4 * (c + 16 * w);

        float v[7][4];
        #pragma unroll
        for (int nn = 0; nn < 4; ++nn) {
            const float z0 = acc[0][nn][0] + bbv[nn];
            const float z1 = acc[0][nn][1];
            const float z2 = acc[0][nn][2];
            const float z3 = acc[0][nn][3];
            const float z4 = acc[1][nn][0];
            const float z5 = acc[1][nn][1];
            const float z6 = acc[1][nn][2];
            const float a  = tanhf(z0);
            const float st = 1.f - a * a;
            const float m2 = -2.f * a * st;
            v[0][nn] = a;
            v[1][nn] = st * z1; v[2][nn] = st * z2; v[3][nn] = st * z3;
            v[4][nn] = fmaf(m2 * z1, z1, st * z4);
            v[5][nn] = fmaf(m2 * z1, z2, st * z5);
            v[6][nn] = fmaf(m2 * z2, z2, st * z6);
        }
        if (l < 2) {
            #pragma unroll
            for (int s = 0; s < 7; ++s) {
                s4v hi, lo;
                #pragma unroll
                for (int nn = 0; nn < 4; ++nn) {
                    const unsigned short h = bf16_rne(v[s][nn]);
                    hi[nn] = (short)h;
                    lo[nn] = (short)bf16_rne(v[s][nn] - bf16f(h));
                }
                const int r = rowof(s, g);
                *(s4v*)&AhS[r * LDA + sbase] = hi;
                *(s4v*)&AlS[r * LDA + sbase] = lo;
            }
        } else {
            #pragma unroll
            for (int s = 0; s < 7; ++s) {
                f32x4 vv = {v[s][0], v[s][1], v[s][2], v[s][3]};
                *(f32x4*)&Zf[rowof(s, g) * LDZ + sbase] = vv;   // final H, f32
            }
        }
        __syncthreads();
    }

    // ---- final layer (256 -> 3): wave w owns point p=w; k strided by lane ----
    const int p = w;
    float part[7][3];
    #pragma unroll
    for (int s = 0; s < 7; ++s)
        #pragma unroll
        for (int m = 0; m < 3; ++m) part[s][m] = 0.f;

    #pragma unroll
    for (int i = 0; i < 4; ++i) {
        const int kslot = lane + 64 * i;
        const int korig = ((kslot >> 6) & 3) * 64 + (kslot & 3) * 16 + ((kslot >> 2) & 15);
        const float w40 = W4[korig * 3 + 0], w41 = W4[korig * 3 + 1], w42 = W4[korig * 3 + 2];
        #pragma unroll
        for (int s = 0; s < 7; ++s) {
            const float hk = Zf[rowof(s, p) * LDZ + kslot];
            part[s][0] = fmaf(hk, w40, part[s][0]);
            part[s][1] = fmaf(hk, w41, part[s][1]);
            part[s][2] = fmaf(hk, w42, part[s][2]);
        }
    }
    #pragma unroll
    for (int s = 0; s < 7; ++s)
        #pragma unroll
        for (int m = 0; m < 3; ++m) {
            float v = part[s][m];
            #pragma unroll
            for (int off = 32; off > 0; off >>= 1) v += __shfl_xor(v, off);
            part[s][m] = v;
        }

    // ---- physics (all lanes redundantly; lane 0 accumulates) ----
    const float x0 = xin[(pt0 + p) * 2 + 0];
    const float x1 = xin[(pt0 + p) * 2 + 1];
    const float tt = tin[pt0 + p];

    const float V0 = part[0][0] + b4[0];
    const float V1 = part[0][1] + b4[1];
    const float V2 = part[0][2] + b4[2];
    const float J00 = part[1][0], J01 = part[2][0], J0t = part[3][0];
    const float J10 = part[1][1], J11 = part[2][1];
    const float J20 = part[1][2], J21 = part[2][2];
    const float H000 = part[4][0], H011 = part[6][0];
    const float H100 = part[4][1], H101 = part[5][1], H111 = part[6][1];
    const float H200 = part[4][2], H201 = part[5][2], H211 = part[6][2];

    const float phi = 1.f / (1.f + expf(-V0));
    const float om  = 1.f - phi;
    const float sp  = phi * om;
    const float spp = sp * (1.f - 2.f * phi);
    const float phx0 = sp * J00, phx1 = sp * J01, dphidt = sp * J0t;
    const float lap = spp * (J00 * J00 + J01 * J01) + sp * (H000 + H011);

    const float ld = tt;
    const float qq = x1 * (x1 - 1.f), qp = 2.f * x1 - 1.f;

    const float ux0 = qq * J10 * ld * (1.f / 3.f);
    const float ux1 = (qp * V1 + qq * J11) * ld * (1.f / 3.f);
    const float uy0 = qq * J20 * ld;
    const float uy1 = (qp * V2 + qq * J21) * ld + ld;

    const float e00 = ux0, e11 = uy1, e01 = 0.5f * (ux1 + uy0);
    const float tr = e00 + e11;

    const float ux_00 = qq * H100 * ld * (1.f / 3.f);
    const float ux_01 = (qp * J10 + qq * H101) * ld * (1.f / 3.f);
    const float ux_11 = (2.f * V1 + 2.f * qp * J11 + qq * H111) * ld * (1.f / 3.f);
    const float uy_00 = qq * H200 * ld;
    const float uy_01 = (qp * J20 + qq * H201) * ld;
    const float uy_11 = (2.f * V2 + 2.f * qp * J21 + qq * H211) * ld;

    const float de00_0 = ux_00, de00_1 = ux_01;
    const float de11_0 = uy_01, de11_1 = uy_11;
    const float de01_0 = 0.5f * (ux_01 + uy_00), de01_1 = 0.5f * (ux_11 + uy_01);
    const float dtr_0 = de00_0 + de11_0, dtr_1 = de00_1 + de11_1;

    const float kk = 2.f;
    const float rtr = fmaxf(tr, 0.f), rntr = fmaxf(-tr, 0.f);
    const float Hp = (tr > 0.f) ? 1.f : 0.f, Hn = (tr < 0.f) ? 1.f : 0.f;

    const float dv = 0.5f * (e00 - e11);
    const float sp00 = kk * rtr + 2.f * dv;
    const float sp11 = kk * rtr - 2.f * dv;
    const float sp01 = 2.f * e01;
    const float snd  = -kk * rntr;

    const float dsp00_0 = kk * Hp * dtr_0 + 2.f * (de00_0 - 0.5f * dtr_0);
    const float dsp01_0 = 2.f * de01_0;
    const float dsp01_1 = 2.f * de01_1;
    const float dsp11_1 = kk * Hp * dtr_1 + 2.f * (de11_1 - 0.5f * dtr_1);
    const float dsn_0 = kk * Hn * dtr_0, dsn_1 = kk * Hn * dtr_1;

    const float cc  = om * om, gg = cc + 1e-6f;
    const float dc0 = -2.f * om * phx0, dc1 = -2.f * om * phx1;
    const float gpc = gg + cc, cg = cc * gg;

    const float res0 = dc0 * gpc * sp00 + cg * dsp00_0 + dc0 * snd + cc * dsn_0
                     + dc1 * gpc * sp01 + cg * dsp01_1;
    const float res1 = dc0 * gpc * sp01 + cg * dsp01_0
                     + dc1 * gpc * sp11 + cg * dsp11_1 + dc1 * snd + cc * dsn_1;

    const float psip = rtr * rtr + 0.5f * (e00 - e11) * (e00 - e11) + 2.f * e01 * e01;
    const float psin = rntr * rntr;

    const float GCc = 0.0027f, LL = 0.02f;
    const float pf = GCc * (phi / LL - LL * lap) - 2.f * om * psip;
    const bool maskp = (fabsf(dphidt) <= 1e-3f) && (fabsf(phi - 1.f) > 1e-3f);
    const bool maskn = fabsf(phi - 1.f) <= 1e-3f;
    const float respf = maskp ? fmaxf(-pf, 0.f) : (maskn ? fmaxf(pf, 0.f) : pf);

    const float rese = om * 2.f * psip + psin
                     + GCc * (phi * phi / (2.f * LL)
                              + 0.5f * LL * (phx0 * phx0 + phx1 * phx1));
    const float irr = fmaxf(-dphidt, 0.f);

    if (lane == 0) {
        float* bin = bins + (blockIdx.x & (NBINS - 1)) * 8;
        atomicAdd(bin + 0, res0 * res0);
        atomicAdd(bin + 1, res1 * res1);
        atomicAdd(bin + 2, respf * respf);
        atomicAdd(bin + 3, rese);
        atomicAdd(bin + 4, irr);
    }

    // ---- fused finalize: last-arriving block reduces the bins ----
    __syncthreads();                          // this block's atomics drained
    if (tid == 0) flagS = atomicAdd(cnt, 1u);
    __syncthreads();
    if (flagS == NBLK - 1 && tid < 64) {
        float s0 = atomicAdd(&bins[tid * 8 + 0], 0.f);
        float s1 = atomicAdd(&bins[tid * 8 + 1], 0.f);
        float s2 = atomicAdd(&bins[tid * 8 + 2], 0.f);
        float s3 = atomicAdd(&bins[tid * 8 + 3], 0.f);
        float s4 = atomicAdd(&bins[tid * 8 + 4], 0.f);
        #pragma unroll
        for (int off = 32; off > 0; off >>= 1) {
            s0 += __shfl_xor(s0, off);
            s1 += __shfl_xor(s1, off);
            s2 += __shfl_xor(s2, off);
            s3 += __shfl_xor(s3, off);
            s4 += __shfl_xor(s4, off);
        }
        if (tid == 0) {
            const float inv_n = 1.f / (float)N_PTS;
            const float mse0 = s0 * inv_n, mse1 = s1 * inv_n;
            const float wm = 0.5f * (mse0 + mse1);
            out[0] = wm * mse0 / (mse0 + 1e-6f) + wm * mse1 / (mse1 + 1e-6f);
            out[1] = s2 * inv_n;
            out[2] = logf(s3);
            out[3] = s4 * inv_n;
        }
    }
}

// ---------------------------------------------------------------------------
extern "C" void kernel_launch(void* const* d_in, const int* in_sizes, int n_in,
                              void* d_out, int out_size, void* d_ws, size_t ws_size,
                              hipStream_t stream)
{
    const float *W[5], *b[5];
    if (in_sizes[1] == HIDDEN) {
        for (int i = 0; i < 5; ++i) {           // dict order W0,b0,W1,b1,...
            W[i] = (const float*)d_in[2 * i];
            b[i] = (const float*)d_in[2 * i + 1];
        }
    } else {
        for (int i = 0; i < 5; ++i) {           // signature order W0..W4, b0..b4
            W[i] = (const float*)d_in[i];
            b[i] = (const float*)d_in[5 + i];
        }
    }
    const float* x = (const float*)d_in[10];
    const float* t = (const float*)d_in[11];
    float* bins = (float*)d_ws;
    unsigned short* Bp = (unsigned short*)((char*)d_ws + BP_OFF);

    pinn_pack<<<384, 64, 0, stream>>>(W[1], W[2], W[3], Bp, bins);
    pinn_main<<<NBLK, THREADS, 0, stream>>>(W[0], b[0], b[1], b[2], b[3],
                                            W[4], b[4], x, t, Bp, bins,
                                            (float*)d_out);
}

// Round 11
// 166.766 us; speedup vs baseline: 1.0743x; 1.0743x over previous
//
#include <hip/hip_runtime.h>
#include <math.h>

#define N_PTS 8192
#define HIDDEN 256
#define PPB 4                   // points per block
#define THREADS 256             // 4 waves
#define NBLK (N_PTS / PPB)      // 2048
#define NBINS 64
#define LDA 264                 // A row stride in shorts (528 B, 16B-aligned)
#define AROWS 32
#define LDZ 264                 // final-H f32 row stride
#define BP_OFF 4096             // byte offset of packed W in d_ws

typedef float f32x4 __attribute__((ext_vector_type(4)));
typedef short s8v  __attribute__((ext_vector_type(8)));
typedef short s4v  __attribute__((ext_vector_type(4)));

__device__ __forceinline__ unsigned short bf16_rne(float x) {
    unsigned int u = __float_as_uint(x);
    return (unsigned short)((u + 0x7FFFu + ((u >> 16) & 1u)) >> 16);
}
__device__ __forceinline__ float bf16f(unsigned short h) {
    return __uint_as_float(((unsigned int)h) << 16);
}
// row of (stream s, point p): point-local, 2 M-tiles, pads at 16+4p+3
__device__ __forceinline__ int rowof(int s, int p) {
    return (s < 4) ? (4 * p + s) : (16 + 4 * p + (s - 4));
}

// ---------------------------------------------------------------------------
// Pack W1..W3 into MFMA B-frag order with the k-slot permutation:
// slot sigma holds neuron j = 64*(sigma>>6) + 16*(sigma&3) + ((sigma>>2)&15).
// Lane l supplies B[k = slot(kc*32 + (l>>4)*8 + i)][n = nt*16 + (l&15)].
// Also zeroes bins + finalize counter (bins[0..519]).
// ---------------------------------------------------------------------------
__global__ void pinn_pack(const float* __restrict__ W1, const float* __restrict__ W2,
                          const float* __restrict__ W3, unsigned short* __restrict__ Bp,
                          float* __restrict__ bins)
{
    const int id = blockIdx.x * 64 + threadIdx.x;    // 0..24575 (384 blocks x 64)
    if (id < 520) bins[id] = 0.f;                    // 512 bins + cnt
    const int lane = id & 63;
    const int nt   = (id >> 6) & 15;
    const int kc   = (id >> 10) & 7;
    const int l    = id >> 13;                        // 0..2
    const float* W = (l == 0) ? W1 : ((l == 1) ? W2 : W3);
    const int n  = nt * 16 + (lane & 15);
    unsigned short hi[8], lo[8];
    #pragma unroll
    for (int i = 0; i < 8; ++i) {
        const int kslot = kc * 32 + (lane >> 4) * 8 + i;
        const int korig = ((kslot >> 6) & 3) * 64 + (kslot & 3) * 16 + ((kslot >> 2) & 15);
        const float x = W[(size_t)korig * HIDDEN + n];
        const unsigned short h = bf16_rne(x);
        hi[i] = h;
        lo[i] = bf16_rne(x - bf16f(h));
    }
    const size_t bh = ((((size_t)(l * 2 + 0) * 8 + kc) * 16 + nt) * 64 + lane) * 8;
    const size_t bl = ((((size_t)(l * 2 + 1) * 8 + kc) * 16 + nt) * 64 + lane) * 8;
    *(s8v*)&Bp[bh] = *(const s8v*)hi;
    *(s8v*)&Bp[bl] = *(const s8v*)lo;
}

// ---------------------------------------------------------------------------
// Main: second-order forward-mode MLP via split-bf16 MFMA + physics.
// PPB=4, 32-row A -> 33.8 KB LDS -> 4 blocks/CU via LDS (NOT via launch_bounds:
// the w=4 hint capped VGPR at 64 and spilled ~19 regs -> 39 MB scratch writes
// in r10.  w=2 keeps the 128-VGPR budget; LDS alone enforces 4 blocks/CU).
// Nonlinearity fully in C-registers (lane g owns point g).
// ---------------------------------------------------------------------------
__global__ __launch_bounds__(THREADS, 2)
void pinn_main(const float* __restrict__ W0, const float* __restrict__ b0,
               const float* __restrict__ b1, const float* __restrict__ b2,
               const float* __restrict__ b3,
               const float* __restrict__ W4, const float* __restrict__ b4,
               const float* __restrict__ xin, const float* __restrict__ tin,
               const unsigned short* __restrict__ Bp,
               float* __restrict__ bins, float* __restrict__ out)
{
    __shared__ __align__(16) unsigned char LB[AROWS * LDA * 4];   // 33792 B
    __shared__ unsigned flagS;
    short* __restrict__ AhS = (short*)LB;
    short* __restrict__ AlS = (short*)(LB + AROWS * LDA * 2);
    float* __restrict__ Zf  = (float*)LB;               // final-H alias (32x264 f32)

    const int tid  = threadIdx.x;
    const int lane = tid & 63;
    const int w    = tid >> 6;          // wave 0..3
    const int c    = lane & 15;
    const int g    = lane >> 4;
    const int pt0  = blockIdx.x * PPB;
    unsigned* cnt  = (unsigned*)(bins + 512);

    // ---- layer 0 (3 -> 256): thread (c0i,w0i) -> slots 4(c0i+16w0i)+nn,
    //      cols j = 64*w0i + 16*nn + c0i; point pp = tid>>6 ----
    {
        const int c0i = tid & 15, w0i = (tid >> 4) & 3, pp = tid >> 6;
        float w0v[4], w1v[4], w2v[4], bbv[4];
        #pragma unroll
        for (int nn = 0; nn < 4; ++nn) {
            const int j = w0i * 64 + 16 * nn + c0i;
            w0v[nn] = W0[j]; w1v[nn] = W0[HIDDEN + j]; w2v[nn] = W0[2 * HIDDEN + j];
            bbv[nn] = b0[j];
        }
        const int sbase = 4 * (c0i + 16 * w0i);
        const float x0 = xin[(pt0 + pp) * 2 + 0];
        const float x1 = xin[(pt0 + pp) * 2 + 1];
        const float tt = tin[pt0 + pp];
        s4v hi[7], lo[7];
        #pragma unroll
        for (int nn = 0; nn < 4; ++nn) {
            const float z  = fmaf(x0, w0v[nn], fmaf(x1, w1v[nn], fmaf(tt, w2v[nn], bbv[nn])));
            const float a  = tanhf(z);
            const float st = 1.f - a * a;
            const float m2 = -2.f * a * st;
            float v[7];
            v[0] = a;
            v[1] = st * w0v[nn]; v[2] = st * w1v[nn]; v[3] = st * w2v[nn];
            v[4] = m2 * w0v[nn] * w0v[nn];
            v[5] = m2 * w0v[nn] * w1v[nn];
            v[6] = m2 * w1v[nn] * w1v[nn];
            #pragma unroll
            for (int s = 0; s < 7; ++s) {
                const unsigned short h = bf16_rne(v[s]);
                hi[s][nn] = (short)h;
                lo[s][nn] = (short)bf16_rne(v[s] - bf16f(h));
            }
        }
        #pragma unroll
        for (int s = 0; s < 7; ++s) {
            const int r = rowof(s, pp);
            *(s4v*)&AhS[r * LDA + sbase] = hi[s];
            *(s4v*)&AlS[r * LDA + sbase] = lo[s];
        }
        const s4v z4 = {0, 0, 0, 0};
        const int rp = 16 + 4 * pp + 3;              // pad row of this point
        *(s4v*)&AhS[rp * LDA + sbase] = z4;
        *(s4v*)&AlS[rp * LDA + sbase] = z4;
    }
    __syncthreads();

    // per-thread A-frag row offsets
    int aoff[2];
    #pragma unroll
    for (int mt = 0; mt < 2; ++mt) aoff[mt] = (16 * mt + c) * LDA + g * 8;

    // ---- hidden layers: split-bf16 MFMA matmul + in-register nonlinearity ----
    for (int l = 0; l < 3; ++l) {
        f32x4 acc[2][4];
        #pragma unroll
        for (int mt = 0; mt < 2; ++mt)
            #pragma unroll
            for (int nn = 0; nn < 4; ++nn) acc[mt][nn] = (f32x4)0.f;

        const size_t lbase = (size_t)l * 2 * 8 * 16 * 64 * 8;
        #pragma unroll
        for (int kc = 0; kc < 8; ++kc) {
            s8v ah[2], al[2];
            #pragma unroll
            for (int mt = 0; mt < 2; ++mt) {
                ah[mt] = *(const s8v*)&AhS[aoff[mt] + kc * 32];
                al[mt] = *(const s8v*)&AlS[aoff[mt] + kc * 32];
            }
            s8v bh[4], bl[4];
            #pragma unroll
            for (int nn = 0; nn < 4; ++nn) {
                const int nt = w * 4 + nn;
                const size_t oh = lbase + (((size_t)kc * 16 + nt) * 64 + lane) * 8;
                const size_t ol = oh + (size_t)8 * 16 * 64 * 8;
                bh[nn] = *(const s8v*)&Bp[oh];
                bl[nn] = *(const s8v*)&Bp[ol];
            }
            #pragma unroll
            for (int mt = 0; mt < 2; ++mt)
                #pragma unroll
                for (int nn = 0; nn < 4; ++nn) {
                    acc[mt][nn] = __builtin_amdgcn_mfma_f32_16x16x32_bf16(ah[mt], bh[nn], acc[mt][nn], 0, 0, 0);
                    acc[mt][nn] = __builtin_amdgcn_mfma_f32_16x16x32_bf16(ah[mt], bl[nn], acc[mt][nn], 0, 0, 0);
                    acc[mt][nn] = __builtin_amdgcn_mfma_f32_16x16x32_bf16(al[mt], bh[nn], acc[mt][nn], 0, 0, 0);
                }
        }
        __syncthreads();                     // all A reads done -> safe to overwrite

        // ---- boundary: lane (c,g) owns point g, cols 64w+16nn+c ----
        const float* bias = (l == 0) ? b1 : (l == 1) ? b2 : b3;
        float bbv[4];
        #pragma unroll
        for (int nn = 0; nn < 4; ++nn) bbv[nn] = bias[64 * w + 16 * nn + c];
        const int sbase = 4 * (c + 16 * w);

        float v[7][4];
        #pragma unroll
        for (int nn = 0; nn < 4; ++nn) {
            const float z0 = acc[0][nn][0] + bbv[nn];
            const float z1 = acc[0][nn][1];
            const float z2 = acc[0][nn][2];
            const float z3 = acc[0][nn][3];
            const float z4 = acc[1][nn][0];
            const float z5 = acc[1][nn][1];
            const float z6 = acc[1][nn][2];
            const float a  = tanhf(z0);
            const float st = 1.f - a * a;
            const float m2 = -2.f * a * st;
            v[0][nn] = a;
            v[1][nn] = st * z1; v[2][nn] = st * z2; v[3][nn] = st * z3;
            v[4][nn] = fmaf(m2 * z1, z1, st * z4);
            v[5][nn] = fmaf(m2 * z1, z2, st * z5);
            v[6][nn] = fmaf(m2 * z2, z2, st * z6);
        }
        if (l < 2) {
            #pragma unroll
            for (int s = 0; s < 7; ++s) {
                s4v hi, lo;
                #pragma unroll
                for (int nn = 0; nn < 4; ++nn) {
                    const unsigned short h = bf16_rne(v[s][nn]);
                    hi[nn] = (short)h;
                    lo[nn] = (short)bf16_rne(v[s][nn] - bf16f(h));
                }
                const int r = rowof(s, g);
                *(s4v*)&AhS[r * LDA + sbase] = hi;
                *(s4v*)&AlS[r * LDA + sbase] = lo;
            }
        } else {
            #pragma unroll
            for (int s = 0; s < 7; ++s) {
                f32x4 vv = {v[s][0], v[s][1], v[s][2], v[s][3]};
                *(f32x4*)&Zf[rowof(s, g) * LDZ + sbase] = vv;   // final H, f32
            }
        }
        __syncthreads();
    }

    // ---- final layer (256 -> 3): wave w owns point p=w; k strided by lane ----
    const int p = w;
    float part[7][3];
    #pragma unroll
    for (int s = 0; s < 7; ++s)
        #pragma unroll
        for (int m = 0; m < 3; ++m) part[s][m] = 0.f;

    #pragma unroll
    for (int i = 0; i < 4; ++i) {
        const int kslot = lane + 64 * i;
        const int korig = ((kslot >> 6) & 3) * 64 + (kslot & 3) * 16 + ((kslot >> 2) & 15);
        const float w40 = W4[korig * 3 + 0], w41 = W4[korig * 3 + 1], w42 = W4[korig * 3 + 2];
        #pragma unroll
        for (int s = 0; s < 7; ++s) {
            const float hk = Zf[rowof(s, p) * LDZ + kslot];
            part[s][0] = fmaf(hk, w40, part[s][0]);
            part[s][1] = fmaf(hk, w41, part[s][1]);
            part[s][2] = fmaf(hk, w42, part[s][2]);
        }
    }
    #pragma unroll
    for (int s = 0; s < 7; ++s)
        #pragma unroll
        for (int m = 0; m < 3; ++m) {
            float v = part[s][m];
            #pragma unroll
            for (int off = 32; off > 0; off >>= 1) v += __shfl_xor(v, off);
            part[s][m] = v;
        }

    // ---- physics (all lanes redundantly; lane 0 accumulates) ----
    const float x0 = xin[(pt0 + p) * 2 + 0];
    const float x1 = xin[(pt0 + p) * 2 + 1];
    const float tt = tin[pt0 + p];

    const float V0 = part[0][0] + b4[0];
    const float V1 = part[0][1] + b4[1];
    const float V2 = part[0][2] + b4[2];
    const float J00 = part[1][0], J01 = part[2][0], J0t = part[3][0];
    const float J10 = part[1][1], J11 = part[2][1];
    const float J20 = part[1][2], J21 = part[2][2];
    const float H000 = part[4][0], H011 = part[6][0];
    const float H100 = part[4][1], H101 = part[5][1], H111 = part[6][1];
    const float H200 = part[4][2], H201 = part[5][2], H211 = part[6][2];

    const float phi = 1.f / (1.f + expf(-V0));
    const float om  = 1.f - phi;
    const float sp  = phi * om;
    const float spp = sp * (1.f - 2.f * phi);
    const float phx0 = sp * J00, phx1 = sp * J01, dphidt = sp * J0t;
    const float lap = spp * (J00 * J00 + J01 * J01) + sp * (H000 + H011);

    const float ld = tt;
    const float qq = x1 * (x1 - 1.f), qp = 2.f * x1 - 1.f;

    const float ux0 = qq * J10 * ld * (1.f / 3.f);
    const float ux1 = (qp * V1 + qq * J11) * ld * (1.f / 3.f);
    const float uy0 = qq * J20 * ld;
    const float uy1 = (qp * V2 + qq * J21) * ld + ld;

    const float e00 = ux0, e11 = uy1, e01 = 0.5f * (ux1 + uy0);
    const float tr = e00 + e11;

    const float ux_00 = qq * H100 * ld * (1.f / 3.f);
    const float ux_01 = (qp * J10 + qq * H101) * ld * (1.f / 3.f);
    const float ux_11 = (2.f * V1 + 2.f * qp * J11 + qq * H111) * ld * (1.f / 3.f);
    const float uy_00 = qq * H200 * ld;
    const float uy_01 = (qp * J20 + qq * H201) * ld;
    const float uy_11 = (2.f * V2 + 2.f * qp * J21 + qq * H211) * ld;

    const float de00_0 = ux_00, de00_1 = ux_01;
    const float de11_0 = uy_01, de11_1 = uy_11;
    const float de01_0 = 0.5f * (ux_01 + uy_00), de01_1 = 0.5f * (ux_11 + uy_01);
    const float dtr_0 = de00_0 + de11_0, dtr_1 = de00_1 + de11_1;

    const float kk = 2.f;
    const float rtr = fmaxf(tr, 0.f), rntr = fmaxf(-tr, 0.f);
    const float Hp = (tr > 0.f) ? 1.f : 0.f, Hn = (tr < 0.f) ? 1.f : 0.f;

    const float dv = 0.5f * (e00 - e11);
    const float sp00 = kk * rtr + 2.f * dv;
    const float sp11 = kk * rtr - 2.f * dv;
    const float sp01 = 2.f * e01;
    const float snd  = -kk * rntr;

    const float dsp00_0 = kk * Hp * dtr_0 + 2.f * (de00_0 - 0.5f * dtr_0);
    const float dsp01_0 = 2.f * de01_0;
    const float dsp01_1 = 2.f * de01_1;
    const float dsp11_1 = kk * Hp * dtr_1 + 2.f * (de11_1 - 0.5f * dtr_1);
    const float dsn_0 = kk * Hn * dtr_0, dsn_1 = kk * Hn * dtr_1;

    const float cc  = om * om, gg = cc + 1e-6f;
    const float dc0 = -2.f * om * phx0, dc1 = -2.f * om * phx1;
    const float gpc = gg + cc, cg = cc * gg;

    const float res0 = dc0 * gpc * sp00 + cg * dsp00_0 + dc0 * snd + cc * dsn_0
                     + dc1 * gpc * sp01 + cg * dsp01_1;
    const float res1 = dc0 * gpc * sp01 + cg * dsp01_0
                     + dc1 * gpc * sp11 + cg * dsp11_1 + dc1 * snd + cc * dsn_1;

    const float psip = rtr * rtr + 0.5f * (e00 - e11) * (e00 - e11) + 2.f * e01 * e01;
    const float psin = rntr * rntr;

    const float GCc = 0.0027f, LL = 0.02f;
    const float pf = GCc * (phi / LL - LL * lap) - 2.f * om * psip;
    const bool maskp = (fabsf(dphidt) <= 1e-3f) && (fabsf(phi - 1.f) > 1e-3f);
    const bool maskn = fabsf(phi - 1.f) <= 1e-3f;
    const float respf = maskp ? fmaxf(-pf, 0.f) : (maskn ? fmaxf(pf, 0.f) : pf);

    const float rese = om * 2.f * psip + psin
                     + GCc * (phi * phi / (2.f * LL)
                              + 0.5f * LL * (phx0 * phx0 + phx1 * phx1));
    const float irr = fmaxf(-dphidt, 0.f);

    if (lane == 0) {
        float* bin = bins + (blockIdx.x & (NBINS - 1)) * 8;
        atomicAdd(bin + 0, res0 * res0);
        atomicAdd(bin + 1, res1 * res1);
        atomicAdd(bin + 2, respf * respf);
        atomicAdd(bin + 3, rese);
        atomicAdd(bin + 4, irr);
    }

    // ---- fused finalize: last-arriving block reduces the bins ----
    __syncthreads();                          // this block's atomics drained
    if (tid == 0) flagS = atomicAdd(cnt, 1u);
    __syncthreads();
    if (flagS == NBLK - 1 && tid < 64) {
        float s0 = atomicAdd(&bins[tid * 8 + 0], 0.f);
        float s1 = atomicAdd(&bins[tid * 8 + 1], 0.f);
        float s2 = atomicAdd(&bins[tid * 8 + 2], 0.f);
        float s3 = atomicAdd(&bins[tid * 8 + 3], 0.f);
        float s4 = atomicAdd(&bins[tid * 8 + 4], 0.f);
        #pragma unroll
        for (int off = 32; off > 0; off >>= 1) {
            s0 += __shfl_xor(s0, off);
            s1 += __shfl_xor(s1, off);
            s2 += __shfl_xor(s2, off);
            s3 += __shfl_xor(s3, off);
            s4 += __shfl_xor(s4, off);
        }
        if (tid == 0) {
            const float inv_n = 1.f / (float)N_PTS;
            const float mse0 = s0 * inv_n, mse1 = s1 * inv_n;
            const float wm = 0.5f * (mse0 + mse1);
            out[0] = wm * mse0 / (mse0 + 1e-6f) + wm * mse1 / (mse1 + 1e-6f);
            out[1] = s2 * inv_n;
            out[2] = logf(s3);
            out[3] = s4 * inv_n;
        }
    }
}

// ---------------------------------------------------------------------------
extern "C" void kernel_launch(void* const* d_in, const int* in_sizes, int n_in,
                              void* d_out, int out_size, void* d_ws, size_t ws_size,
                              hipStream_t stream)
{
    const float *W[5], *b[5];
    if (in_sizes[1] == HIDDEN) {
        for (int i = 0; i < 5; ++i) {           // dict order W0,b0,W1,b1,...
            W[i] = (const float*)d_in[2 * i];
            b[i] = (const float*)d_in[2 * i + 1];
        }
    } else {
        for (int i = 0; i < 5; ++i) {           // signature order W0..W4, b0..b4
            W[i] = (const float*)d_in[i];
            b[i] = (const float*)d_in[5 + i];
        }
    }
    const float* x = (const float*)d_in[10];
    const float* t = (const float*)d_in[11];
    float* bins = (float*)d_ws;
    unsigned short* Bp = (unsigned short*)((char*)d_ws + BP_OFF);

    pinn_pack<<<384, 64, 0, stream>>>(W[1], W[2], W[3], Bp, bins);
    pinn_main<<<NBLK, THREADS, 0, stream>>>(W[0], b[0], b[1], b[2], b[3],
                                            W[4], b[4], x, t, Bp, bins,
                                            (float*)d_out);
}